// Round 1
// baseline (200.824 us; speedup 1.0000x reference)
//
#include <hip/hip_runtime.h>

typedef __bf16 bf16x8 __attribute__((ext_vector_type(8)));
typedef __bf16 bf16x4 __attribute__((ext_vector_type(4)));
typedef float  f32x4  __attribute__((ext_vector_type(4)));

#define NPIX  3136      // 56*56, = 49 * 64 exactly (no tails anywhere)
#define WIMG  56
#define CCH   128
#define NH    4
#define HD    32
#define SCALE 0.17677669529663687f  // 32^-0.5, folded into qT at store time

// ---------------------------------------------------------------------------
// K1: qkv = qkv_w @ x + qkv_b  (fp32 vector GEMM, M=384 K=128 N=6272)
// Writes qT/kT as [b*4+h][N][32] bf16 (q pre-scaled), v as [b][c][N] bf16.
// grid (13, 12, 2), block (64, 4): thread tile = 4 pixels x 8 outputs.
// ---------------------------------------------------------------------------
__global__ __launch_bounds__(256) void k_qkv(
    const float* __restrict__ x, const float* __restrict__ qkv_w,
    const float* __restrict__ qkv_b,
    __bf16* __restrict__ qT, __bf16* __restrict__ kT, __bf16* __restrict__ vB)
{
    __shared__ float wT[CCH * 32];                 // [c][o'] o' in 0..31
    const int tx = threadIdx.x, ty = threadIdx.y;
    const int tid = tx + ty * 64;
    const int yblk = blockIdx.y;                   // 32-output slab
    const int b = blockIdx.z;
    const int o0blk = yblk * 32;

    #pragma unroll
    for (int i = 0; i < 16; ++i) {                 // coop-load W^T tile (16 KB)
        int idx = tid + i * 256;
        int op = idx >> 7, c = idx & 127;
        wT[c * 32 + op] = qkv_w[(o0blk + op) * CCH + c];
    }
    __syncthreads();

    const int n0 = blockIdx.x * 256 + tx * 4;
    if (n0 >= NPIX) return;

    float acc[8][4];
    #pragma unroll
    for (int j = 0; j < 8; ++j)
        #pragma unroll
        for (int i = 0; i < 4; ++i) acc[j][i] = 0.f;

    const float* xb = x + (size_t)b * CCH * NPIX + n0;
    const float* wrow = wT + ty * 8;
    #pragma unroll 2
    for (int c = 0; c < CCH; ++c) {
        const float4 xv = *(const float4*)(xb + (size_t)c * NPIX);
        const float4 wA = *(const float4*)(wrow + c * 32);
        const float4 wB = *(const float4*)(wrow + c * 32 + 4);
        const float wv[8] = {wA.x, wA.y, wA.z, wA.w, wB.x, wB.y, wB.z, wB.w};
        #pragma unroll
        for (int j = 0; j < 8; ++j) {
            acc[j][0] += wv[j] * xv.x;  acc[j][1] += wv[j] * xv.y;
            acc[j][2] += wv[j] * xv.z;  acc[j][3] += wv[j] * xv.w;
        }
    }

    const int d0 = ty * 8;
    float bias[8];
    #pragma unroll
    for (int j = 0; j < 8; ++j) bias[j] = qkv_b[o0blk + d0 + j];

    if (yblk < 4) {                                    // ---- q (scaled) ----
        __bf16* dst = qT + (size_t)(b * NH + yblk) * NPIX * HD + d0;
        #pragma unroll
        for (int i = 0; i < 4; ++i) {
            bf16x8 v;
            #pragma unroll
            for (int j = 0; j < 8; ++j) v[j] = (__bf16)((acc[j][i] + bias[j]) * SCALE);
            *(bf16x8*)(dst + (size_t)(n0 + i) * HD) = v;
        }
    } else if (yblk < 8) {                             // ---- k ----
        __bf16* dst = kT + (size_t)(b * NH + (yblk - 4)) * NPIX * HD + d0;
        #pragma unroll
        for (int i = 0; i < 4; ++i) {
            bf16x8 v;
            #pragma unroll
            for (int j = 0; j < 8; ++j) v[j] = (__bf16)(acc[j][i] + bias[j]);
            *(bf16x8*)(dst + (size_t)(n0 + i) * HD) = v;
        }
    } else {                                           // ---- v ----
        #pragma unroll
        for (int j = 0; j < 8; ++j) {
            const int c = (yblk - 8) * 32 + d0 + j;
            bf16x4 v;
            #pragma unroll
            for (int i = 0; i < 4; ++i) v[i] = (__bf16)(acc[j][i] + bias[j]);
            *(bf16x4*)(vB + (size_t)(b * CCH + c) * NPIX + n0) = v;
        }
    }
}

// ---------------------------------------------------------------------------
// K2: flash attention, bf16 MFMA 16x16x32 (K=32 = full head_dim).
// grid (49, 8), block 256 = 4 waves; each wave owns 16 queries, fully
// wave-private (no __syncthreads). No online max: logits bounded (~|s|<0.3),
// p = exp(s), normalize by row-sum in epilogue.
// Layouts (verified m89/m91/m120): A-frag A[m=lane&15][k=(lane>>4)*8+j],
// B-frag B[k=(lane>>4)*8+j][n=lane&15], C/D col=lane&15 row=(lane>>4)*4+reg.
// ---------------------------------------------------------------------------
__global__ __launch_bounds__(256) void k_attn(
    const __bf16* __restrict__ qT, const __bf16* __restrict__ kT,
    const __bf16* __restrict__ vB, float* __restrict__ attn_out)
{
    __shared__ __bf16 P[4][16][72];   // per-wave P tile, +8 pad (banks, 16B-aligned rows)
    const int tid  = threadIdx.x;
    const int w    = tid >> 6, lane = tid & 63;
    const int col  = lane & 15, g = lane >> 4;
    const int bh   = blockIdx.y;
    const int b    = bh >> 2, h = bh & 3;
    const int qbase = blockIdx.x * 64 + w * 16;
    const size_t headoff = (size_t)bh * NPIX * HD;

    // Q A-fragment: rows qbase..qbase+15, lives in registers for whole block
    const bf16x8 aq = *(const bf16x8*)(qT + headoff + (size_t)(qbase + col) * HD + g * 8);

    f32x4 O0 = {0.f, 0.f, 0.f, 0.f}, O1 = {0.f, 0.f, 0.f, 0.f};
    float lacc[4] = {0.f, 0.f, 0.f, 0.f};

    const __bf16* kTh   = kT + headoff;
    const __bf16* vrow0 = vB + (size_t)(b * CCH + h * HD + col)      * NPIX;  // d = col
    const __bf16* vrow1 = vB + (size_t)(b * CCH + h * HD + 16 + col) * NPIX;  // d = col+16

    for (int k0 = 0; k0 < NPIX; k0 += 64) {
        const bf16x8 bk0 = *(const bf16x8*)(kTh + (size_t)(k0      + col) * HD + g * 8);
        const bf16x8 bk1 = *(const bf16x8*)(kTh + (size_t)(k0 + 16 + col) * HD + g * 8);
        const bf16x8 bk2 = *(const bf16x8*)(kTh + (size_t)(k0 + 32 + col) * HD + g * 8);
        const bf16x8 bk3 = *(const bf16x8*)(kTh + (size_t)(k0 + 48 + col) * HD + g * 8);
        const bf16x8 bv00 = *(const bf16x8*)(vrow0 + k0      + g * 8);  // keys 0..31
        const bf16x8 bv10 = *(const bf16x8*)(vrow0 + k0 + 32 + g * 8);  // keys 32..63
        const bf16x8 bv01 = *(const bf16x8*)(vrow1 + k0      + g * 8);
        const bf16x8 bv11 = *(const bf16x8*)(vrow1 + k0 + 32 + g * 8);

        const f32x4 z = {0.f, 0.f, 0.f, 0.f};
        f32x4 s0 = __builtin_amdgcn_mfma_f32_16x16x32_bf16(aq, bk0, z, 0, 0, 0);
        f32x4 s1 = __builtin_amdgcn_mfma_f32_16x16x32_bf16(aq, bk1, z, 0, 0, 0);
        f32x4 s2 = __builtin_amdgcn_mfma_f32_16x16x32_bf16(aq, bk2, z, 0, 0, 0);
        f32x4 s3 = __builtin_amdgcn_mfma_f32_16x16x32_bf16(aq, bk3, z, 0, 0, 0);

        #pragma unroll
        for (int r = 0; r < 4; ++r) {
            const float p0 = __expf(s0[r]), p1 = __expf(s1[r]);
            const float p2 = __expf(s2[r]), p3 = __expf(s3[r]);
            lacc[r] += (p0 + p1) + (p2 + p3);
            const int q = g * 4 + r;                 // C-layout row
            P[w][q][ 0 + col] = (__bf16)p0;
            P[w][q][16 + col] = (__bf16)p1;
            P[w][q][32 + col] = (__bf16)p2;
            P[w][q][48 + col] = (__bf16)p3;
        }
        // read P back in A-layout (wave-private, in-order DS => no barrier)
        const bf16x8 ap0 = *(const bf16x8*)&P[w][col][     g * 8];
        const bf16x8 ap1 = *(const bf16x8*)&P[w][col][32 + g * 8];

        O0 = __builtin_amdgcn_mfma_f32_16x16x32_bf16(ap0, bv00, O0, 0, 0, 0);
        O0 = __builtin_amdgcn_mfma_f32_16x16x32_bf16(ap1, bv10, O0, 0, 0, 0);
        O1 = __builtin_amdgcn_mfma_f32_16x16x32_bf16(ap0, bv01, O1, 0, 0, 0);
        O1 = __builtin_amdgcn_mfma_f32_16x16x32_bf16(ap1, bv11, O1, 0, 0, 0);
    }

    // row-sum reduce across the 16 lanes of each group (cols), then 1/l
    #pragma unroll
    for (int r = 0; r < 4; ++r) {
        float l = lacc[r];
        l += __shfl_xor(l, 1);  l += __shfl_xor(l, 2);
        l += __shfl_xor(l, 4);  l += __shfl_xor(l, 8);
        lacc[r] = 1.0f / l;
    }

    float* obase = attn_out + (size_t)(b * CCH + h * HD) * NPIX;
    #pragma unroll
    for (int r = 0; r < 4; ++r) {
        const int qg = qbase + g * 4 + r;
        obase[(size_t)col        * NPIX + qg] = O0[r] * lacc[r];
        obase[(size_t)(col + 16) * NPIX + qg] = O1[r] * lacc[r];
    }
}

// ---------------------------------------------------------------------------
// K3: LePE 5x5 depthwise conv on v (bf16) + bias, added in-place to attn_out.
// grid (13, 128, 2), block 256, one pixel per thread.
// ---------------------------------------------------------------------------
__global__ __launch_bounds__(256) void k_lepe(
    const __bf16* __restrict__ vB, const float* __restrict__ lepe_w,
    const float* __restrict__ lepe_b, float* __restrict__ attn)
{
    const int n = blockIdx.x * 256 + threadIdx.x;
    if (n >= NPIX) return;
    const int c = blockIdx.y, b = blockIdx.z;
    const int y = n / WIMG, x0 = n % WIMG;
    const __bf16* vrow = vB + (size_t)(b * CCH + c) * NPIX;
    const float* wv = lepe_w + c * 25;
    float acc = lepe_b[c];
    #pragma unroll
    for (int dy = 0; dy < 5; ++dy) {
        const int yy = y + dy - 2;
        if (yy < 0 || yy >= WIMG) continue;
        #pragma unroll
        for (int dx = 0; dx < 5; ++dx) {
            const int xx = x0 + dx - 2;
            if (xx < 0 || xx >= WIMG) continue;
            acc += (float)vrow[yy * WIMG + xx] * wv[dy * 5 + dx];
        }
    }
    const size_t idx = (size_t)(b * CCH + c) * NPIX + n;
    attn[idx] += acc;
}

// ---------------------------------------------------------------------------
// K4: out = proj_w @ (attn_out) + proj_b  (fp32 vector GEMM, M=128 K=128)
// grid (13, 8, 2), block (64, 4): thread tile = 4 pixels x 4 outputs.
// ---------------------------------------------------------------------------
__global__ __launch_bounds__(256) void k_proj(
    const float* __restrict__ attn, const float* __restrict__ proj_w,
    const float* __restrict__ proj_b, float* __restrict__ out)
{
    __shared__ float wT[CCH * 16];
    const int tx = threadIdx.x, ty = threadIdx.y;
    const int tid = tx + ty * 64;
    const int b = blockIdx.z;
    const int o0blk = blockIdx.y * 16;

    #pragma unroll
    for (int i = 0; i < 8; ++i) {
        int idx = tid + i * 256;
        int op = idx >> 7, c = idx & 127;
        wT[c * 16 + op] = proj_w[(o0blk + op) * CCH + c];
    }
    __syncthreads();

    const int n0 = blockIdx.x * 256 + tx * 4;
    if (n0 >= NPIX) return;

    float acc[4][4];
    #pragma unroll
    for (int j = 0; j < 4; ++j)
        #pragma unroll
        for (int i = 0; i < 4; ++i) acc[j][i] = 0.f;

    const float* ab = attn + (size_t)b * CCH * NPIX + n0;
    const float* wrow = wT + ty * 4;
    #pragma unroll 2
    for (int c = 0; c < CCH; ++c) {
        const float4 xv = *(const float4*)(ab + (size_t)c * NPIX);
        const float4 wv = *(const float4*)(wrow + c * 16);
        const float wj[4] = {wv.x, wv.y, wv.z, wv.w};
        #pragma unroll
        for (int j = 0; j < 4; ++j) {
            acc[j][0] += wj[j] * xv.x;  acc[j][1] += wj[j] * xv.y;
            acc[j][2] += wj[j] * xv.z;  acc[j][3] += wj[j] * xv.w;
        }
    }

    #pragma unroll
    for (int j = 0; j < 4; ++j) {
        const int o = o0blk + ty * 4 + j;
        const float pb = proj_b[o];
        float4 r = {acc[j][0] + pb, acc[j][1] + pb, acc[j][2] + pb, acc[j][3] + pb};
        *(float4*)(out + (size_t)(b * CCH + o) * NPIX + n0) = r;
    }
}

// ---------------------------------------------------------------------------
extern "C" void kernel_launch(void* const* d_in, const int* in_sizes, int n_in,
                              void* d_out, int out_size, void* d_ws, size_t ws_size,
                              hipStream_t stream)
{
    const float* x      = (const float*)d_in[0];
    const float* qkv_w  = (const float*)d_in[1];
    const float* qkv_b  = (const float*)d_in[2];
    const float* lepe_w = (const float*)d_in[3];
    const float* lepe_b = (const float*)d_in[4];
    const float* proj_w = (const float*)d_in[5];
    const float* proj_b = (const float*)d_in[6];
    float* out = (float*)d_out;

    // workspace carve (≈8 MB total)
    char* p = (char*)d_ws;
    __bf16* qT = (__bf16*)p;  p += (size_t)2 * NH * NPIX * HD * 2;   // 1.6 MB
    __bf16* kT = (__bf16*)p;  p += (size_t)2 * NH * NPIX * HD * 2;   // 1.6 MB
    __bf16* vB = (__bf16*)p;  p += (size_t)2 * CCH * NPIX * 2;       // 1.6 MB
    float* attn = (float*)p;                                         // 3.2 MB

    k_qkv <<<dim3(13, 12, 2), dim3(64, 4), 0, stream>>>(x, qkv_w, qkv_b, qT, kT, vB);
    k_attn<<<dim3(49, 8),     dim3(256),   0, stream>>>(qT, kT, vB, attn);
    k_lepe<<<dim3(13, CCH, 2), dim3(256),  0, stream>>>(vB, lepe_w, lepe_b, attn);
    k_proj<<<dim3(13, 8, 2),  dim3(64, 4), 0, stream>>>(attn, proj_w, proj_b, out);
}

// Round 2
// 153.803 us; speedup vs baseline: 1.3057x; 1.3057x over previous
//
#include <hip/hip_runtime.h>

typedef __bf16 bf16x8 __attribute__((ext_vector_type(8)));
typedef __bf16 bf16x4 __attribute__((ext_vector_type(4)));
typedef float  f32x4  __attribute__((ext_vector_type(4)));

#define NPIX  3136      // 56*56 = 49*64 = 98*32 (no tails)
#define WIMG  56
#define CCH   128
#define NH    4
#define HD    32
// 32^-0.5 * log2(e): q pre-scaled so softmax uses exp2 directly
#define QSCALE 0.2550565470841439f

#if __has_builtin(__builtin_amdgcn_exp2f)
#define FEXP2(x) __builtin_amdgcn_exp2f(x)
#else
#define FEXP2(x) __expf((x) * 0.6931471805599453f)
#endif

// Key permutation within each 64-key block: storage position s holds key
// K(s) = 16*(s&3) + (s>>2).  QK chunk-c MFMA yields key 16c+col at lane col,
// stored at s=4*col+c => contiguous ds_write_b64 per lane.  V is pre-permuted
// (vP) so PV B-fragments are contiguous bf16x8 loads.  Permuting the
// summation index is mathematically free.

// ---------------------------------------------------------------------------
// K1: qkv = qkv_w @ x + qkv_b (fp32 vector GEMM, M=384 K=128 N=6272)
// grid (13, 24, 2), block (64,4): thread = 4 pixels x 4 outputs.
// yblk 0-7: q (scaled, bf16), 8-15: k, 16-23: v (normal vB + permuted vP).
// ---------------------------------------------------------------------------
__global__ __launch_bounds__(256) void k_qkv(
    const float* __restrict__ x, const float* __restrict__ qkv_w,
    const float* __restrict__ qkv_b,
    __bf16* __restrict__ qT, __bf16* __restrict__ kT,
    __bf16* __restrict__ vB, __bf16* __restrict__ vP)
{
    __shared__ float wT[CCH * 16];                 // [c][op]
    const int tx = threadIdx.x, ty = threadIdx.y;
    const int tid = tx + ty * 64;
    const int yblk = blockIdx.y, b = blockIdx.z;
    const int o0blk = yblk * 16;

    #pragma unroll
    for (int i = 0; i < 8; ++i) {
        int idx = tid + i * 256;
        int op = idx >> 7, c = idx & 127;          // consecutive tid -> consecutive c (coalesced)
        wT[c * 16 + op] = qkv_w[(o0blk + op) * CCH + c];
    }
    __syncthreads();

    const int n0 = blockIdx.x * 256 + tx * 4;
    if (n0 >= NPIX) return;

    float acc[4][4];                               // [out j][pix i]
    #pragma unroll
    for (int j = 0; j < 4; ++j)
        #pragma unroll
        for (int i = 0; i < 4; ++i) acc[j][i] = 0.f;

    const float* xb = x + (size_t)b * CCH * NPIX + n0;
    const float* wrow = wT + ty * 4;
    #pragma unroll 4
    for (int c = 0; c < CCH; ++c) {
        const float4 xv = *(const float4*)(xb + (size_t)c * NPIX);
        const float4 wv = *(const float4*)(wrow + c * 16);   // wave-uniform -> LDS broadcast
        const float wj[4] = {wv.x, wv.y, wv.z, wv.w};
        #pragma unroll
        for (int j = 0; j < 4; ++j) {
            acc[j][0] += wj[j] * xv.x;  acc[j][1] += wj[j] * xv.y;
            acc[j][2] += wj[j] * xv.z;  acc[j][3] += wj[j] * xv.w;
        }
    }

    float bias[4];
    #pragma unroll
    for (int j = 0; j < 4; ++j) bias[j] = qkv_b[o0blk + ty * 4 + j];

    if (yblk < 8) {                                    // ---- q (scaled) ----
        const int h = o0blk >> 5;
        const int d0 = (o0blk & 31) + ty * 4;
        __bf16* dst = qT + (size_t)(b * NH + h) * NPIX * HD + d0;
        #pragma unroll
        for (int i = 0; i < 4; ++i) {
            bf16x4 v;
            #pragma unroll
            for (int j = 0; j < 4; ++j) v[j] = (__bf16)((acc[j][i] + bias[j]) * QSCALE);
            *(bf16x4*)(dst + (size_t)(n0 + i) * HD) = v;
        }
    } else if (yblk < 16) {                            // ---- k ----
        const int o0 = o0blk - 128;
        const int h = o0 >> 5;
        const int d0 = (o0 & 31) + ty * 4;
        __bf16* dst = kT + (size_t)(b * NH + h) * NPIX * HD + d0;
        #pragma unroll
        for (int i = 0; i < 4; ++i) {
            bf16x4 v;
            #pragma unroll
            for (int j = 0; j < 4; ++j) v[j] = (__bf16)(acc[j][i] + bias[j]);
            *(bf16x4*)(dst + (size_t)(n0 + i) * HD) = v;
        }
    } else {                                           // ---- v ----
        const int c0 = o0blk - 256 + ty * 4;
        const int k0 = n0 & ~63;                       // permuted-block base
        const int a  = (n0 >> 4) & 3;
        const int sb = 4 * (n0 & 15) + a;              // s(n0); s(n0+i) = sb + 4i
        #pragma unroll
        for (int j = 0; j < 4; ++j) {
            const int c = c0 + j;
            bf16x4 v;
            #pragma unroll
            for (int i = 0; i < 4; ++i) v[i] = (__bf16)(acc[j][i] + bias[j]);
            *(bf16x4*)(vB + (size_t)(b * CCH + c) * NPIX + n0) = v;
            __bf16* vp = vP + (size_t)(b * CCH + c) * NPIX + k0;
            #pragma unroll
            for (int i = 0; i < 4; ++i) vp[sb + 4 * i] = v[i];
        }
    }
}

// ---------------------------------------------------------------------------
// K2: flash attention, split-K across the 4 waves of a block.
// grid (98, 8), block 256. Block = 32 queries; wave w handles key-chunks
// [49w/4, 49(w+1)/4) of 64 keys each. No-max softmax => partial (O,l) sums
// combine linearly in an LDS reduction epilogue.
// ---------------------------------------------------------------------------
__global__ __launch_bounds__(256) void k_attn(
    const __bf16* __restrict__ qT, const __bf16* __restrict__ kT,
    const __bf16* __restrict__ vP, __bf16* __restrict__ attn_out)
{
    __shared__ __bf16 P[4][32][72];        // per-wave P tile (pad 8 -> 16B rows, 2-way banks)
    __shared__ float  Opart[4][32][33];    // +1 pad: epilogue reads stride-33
    __shared__ float  lpart[4][32];

    const int tid  = threadIdx.x;
    const int w    = tid >> 6, lane = tid & 63;
    const int col  = lane & 15, g = lane >> 4;
    const int bh   = blockIdx.y;
    const int b    = bh >> 2, h = bh & 3;
    const int qbase = blockIdx.x * 32;
    const size_t headoff = (size_t)bh * NPIX * HD;

    const bf16x8 aqA = *(const bf16x8*)(qT + headoff + (size_t)(qbase + col) * HD + g * 8);
    const bf16x8 aqB = *(const bf16x8*)(qT + headoff + (size_t)(qbase + 16 + col) * HD + g * 8);

    f32x4 O[2][2];                          // [qhalf][dhalf]
    #pragma unroll
    for (int i = 0; i < 2; ++i)
        #pragma unroll
        for (int j = 0; j < 2; ++j) O[i][j] = (f32x4){0.f, 0.f, 0.f, 0.f};
    float lacc[2][4] = {{0.f,0.f,0.f,0.f},{0.f,0.f,0.f,0.f}};

    const __bf16* kTh   = kT + headoff;
    const __bf16* vrow0 = vP + (size_t)(b * CCH + h * HD + col)      * NPIX;
    const __bf16* vrow1 = vP + (size_t)(b * CCH + h * HD + 16 + col) * NPIX;

    const int c0 = (49 * w) >> 2, c1 = (49 * (w + 1)) >> 2;   // 12,12,12,13 chunks

    for (int cc = c0; cc < c1; ++cc) {
        const int k0 = cc * 64;
        bf16x8 bk[4], bv[4];
        #pragma unroll
        for (int c = 0; c < 4; ++c)
            bk[c] = *(const bf16x8*)(kTh + (size_t)(k0 + 16 * c + col) * HD + g * 8);
        bv[0] = *(const bf16x8*)(vrow0 + k0      + g * 8);   // dhalf0, keys s0-31
        bv[1] = *(const bf16x8*)(vrow0 + k0 + 32 + g * 8);   // dhalf0, keys s32-63
        bv[2] = *(const bf16x8*)(vrow1 + k0      + g * 8);
        bv[3] = *(const bf16x8*)(vrow1 + k0 + 32 + g * 8);

        const f32x4 z = {0.f, 0.f, 0.f, 0.f};
        #pragma unroll
        for (int qh = 0; qh < 2; ++qh) {
            const bf16x8 aq = qh ? aqB : aqA;
            f32x4 s[4];
            #pragma unroll
            for (int c = 0; c < 4; ++c)
                s[c] = __builtin_amdgcn_mfma_f32_16x16x32_bf16(aq, bk[c], z, 0, 0, 0);
            #pragma unroll
            for (int r = 0; r < 4; ++r) {
                const float p0 = FEXP2(s[0][r]), p1 = FEXP2(s[1][r]);
                const float p2 = FEXP2(s[2][r]), p3 = FEXP2(s[3][r]);
                lacc[qh][r] += (p0 + p1) + (p2 + p3);
                bf16x4 pv = {(__bf16)p0, (__bf16)p1, (__bf16)p2, (__bf16)p3};
                *(bf16x4*)&P[w][qh * 16 + g * 4 + r][4 * col] = pv;   // one b64
            }
        }
        #pragma unroll
        for (int qh = 0; qh < 2; ++qh) {
            const bf16x8 ap0 = *(const bf16x8*)&P[w][qh * 16 + col][g * 8];
            const bf16x8 ap1 = *(const bf16x8*)&P[w][qh * 16 + col][32 + g * 8];
            O[qh][0] = __builtin_amdgcn_mfma_f32_16x16x32_bf16(ap0, bv[0], O[qh][0], 0, 0, 0);
            O[qh][0] = __builtin_amdgcn_mfma_f32_16x16x32_bf16(ap1, bv[1], O[qh][0], 0, 0, 0);
            O[qh][1] = __builtin_amdgcn_mfma_f32_16x16x32_bf16(ap0, bv[2], O[qh][1], 0, 0, 0);
            O[qh][1] = __builtin_amdgcn_mfma_f32_16x16x32_bf16(ap1, bv[3], O[qh][1], 0, 0, 0);
        }
    }

    // partial row-sums across the 16 col-lanes; store per-wave partials
    #pragma unroll
    for (int qh = 0; qh < 2; ++qh)
        #pragma unroll
        for (int r = 0; r < 4; ++r) {
            float l = lacc[qh][r];
            l += __shfl_xor(l, 1);  l += __shfl_xor(l, 2);
            l += __shfl_xor(l, 4);  l += __shfl_xor(l, 8);
            if (col == 0) lpart[w][qh * 16 + g * 4 + r] = l;
        }
    #pragma unroll
    for (int qh = 0; qh < 2; ++qh)
        #pragma unroll
        for (int r = 0; r < 4; ++r) {
            Opart[w][qh * 16 + g * 4 + r][col]      = O[qh][0][r];
            Opart[w][qh * 16 + g * 4 + r][col + 16] = O[qh][1][r];
        }
    __syncthreads();

    // reduce 4 wave-partials, normalize, store bf16 [b][c][pix]
    const int q = tid & 31, dbase = tid >> 5;          // 32 q x 8 d-slots
    const float lt = lpart[0][q] + lpart[1][q] + lpart[2][q] + lpart[3][q];
    const float inv = 1.0f / lt;
    __bf16* obase = attn_out + (size_t)(b * CCH + h * HD) * NPIX + qbase;
    #pragma unroll
    for (int dd = 0; dd < 4; ++dd) {
        const int d = dbase + dd * 8;
        const float o = Opart[0][q][d] + Opart[1][q][d] + Opart[2][q][d] + Opart[3][q][d];
        obase[(size_t)d * NPIX + q] = (__bf16)(o * inv);
    }
}

// ---------------------------------------------------------------------------
// K3: LePE 5x5 depthwise conv on v (normal layout) + bias, += into attn (bf16).
// ---------------------------------------------------------------------------
__global__ __launch_bounds__(256) void k_lepe(
    const __bf16* __restrict__ vB, const float* __restrict__ lepe_w,
    const float* __restrict__ lepe_b, __bf16* __restrict__ attn)
{
    const int n = blockIdx.x * 256 + threadIdx.x;
    if (n >= NPIX) return;
    const int c = blockIdx.y, b = blockIdx.z;
    const int y = n / WIMG, x0 = n % WIMG;
    const __bf16* vrow = vB + (size_t)(b * CCH + c) * NPIX;
    const float* wv = lepe_w + c * 25;                 // c uniform -> scalar loads
    float acc = lepe_b[c];
    #pragma unroll
    for (int dy = 0; dy < 5; ++dy) {
        const int yy = y + dy - 2;
        if (yy < 0 || yy >= WIMG) continue;
        #pragma unroll
        for (int dx = 0; dx < 5; ++dx) {
            const int xx = x0 + dx - 2;
            if (xx < 0 || xx >= WIMG) continue;
            acc += (float)vrow[yy * WIMG + xx] * wv[dy * 5 + dx];
        }
    }
    const size_t idx = (size_t)(b * CCH + c) * NPIX + n;
    attn[idx] = (__bf16)((float)attn[idx] + acc);
}

// ---------------------------------------------------------------------------
// K4: out = proj_w @ attn + proj_b (fp32 vector GEMM, M=128 K=128).
// grid (13, 32, 2), block (64,4): thread = 4 pixels x 1 output (occupancy).
// ---------------------------------------------------------------------------
__global__ __launch_bounds__(256) void k_proj(
    const __bf16* __restrict__ attn, const float* __restrict__ proj_w,
    const float* __restrict__ proj_b, float* __restrict__ out)
{
    __shared__ float wT[CCH * 4];                      // [c][op]
    const int tx = threadIdx.x, ty = threadIdx.y;
    const int tid = tx + ty * 64;
    const int b = blockIdx.z;
    const int o0 = blockIdx.y * 4;

    #pragma unroll
    for (int i = 0; i < 2; ++i) {
        int idx = tid + i * 256;
        int op = idx >> 7, c = idx & 127;
        wT[c * 4 + op] = proj_w[(o0 + op) * CCH + c];
    }
    __syncthreads();

    const int n0 = blockIdx.x * 256 + tx * 4;
    if (n0 >= NPIX) return;

    float acc[4] = {0.f, 0.f, 0.f, 0.f};
    const __bf16* ab = attn + (size_t)b * CCH * NPIX + n0;
    #pragma unroll 4
    for (int c = 0; c < CCH; ++c) {
        const bf16x4 xv = *(const bf16x4*)(ab + (size_t)c * NPIX);
        const float wj = wT[c * 4 + ty];               // wave-uniform -> broadcast
        acc[0] += wj * (float)xv[0];  acc[1] += wj * (float)xv[1];
        acc[2] += wj * (float)xv[2];  acc[3] += wj * (float)xv[3];
    }

    const int o = o0 + ty;
    const float pb = proj_b[o];
    float4 r = {acc[0] + pb, acc[1] + pb, acc[2] + pb, acc[3] + pb};
    *(float4*)(out + (size_t)(b * CCH + o) * NPIX + n0) = r;
}

// ---------------------------------------------------------------------------
extern "C" void kernel_launch(void* const* d_in, const int* in_sizes, int n_in,
                              void* d_out, int out_size, void* d_ws, size_t ws_size,
                              hipStream_t stream)
{
    const float* x      = (const float*)d_in[0];
    const float* qkv_w  = (const float*)d_in[1];
    const float* qkv_b  = (const float*)d_in[2];
    const float* lepe_w = (const float*)d_in[3];
    const float* lepe_b = (const float*)d_in[4];
    const float* proj_w = (const float*)d_in[5];
    const float* proj_b = (const float*)d_in[6];
    float* out = (float*)d_out;

    // workspace carve (8.03 MB, same footprint as the passing R1 kernel)
    char* p = (char*)d_ws;
    __bf16* qT = (__bf16*)p;  p += (size_t)2 * NH * NPIX * HD * 2;   // 1.6 MB
    __bf16* kT = (__bf16*)p;  p += (size_t)2 * NH * NPIX * HD * 2;   // 1.6 MB
    __bf16* vB = (__bf16*)p;  p += (size_t)2 * CCH * NPIX * 2;       // 1.6 MB
    __bf16* vP = (__bf16*)p;  p += (size_t)2 * CCH * NPIX * 2;       // 1.6 MB
    __bf16* attnB = (__bf16*)p;                                      // 1.6 MB

    k_qkv <<<dim3(13, 24, 2),  dim3(64, 4), 0, stream>>>(x, qkv_w, qkv_b, qT, kT, vB, vP);
    k_attn<<<dim3(98, 8),      dim3(256),   0, stream>>>(qT, kT, vP, attnB);
    k_lepe<<<dim3(13, CCH, 2), dim3(256),   0, stream>>>(vB, lepe_w, lepe_b, attnB);
    k_proj<<<dim3(13, 32, 2),  dim3(64, 4), 0, stream>>>(attnB, proj_w, proj_b, out);
}

// Round 3
// 133.693 us; speedup vs baseline: 1.5021x; 1.1504x over previous
//
#include <hip/hip_runtime.h>

typedef __bf16 bf16x8 __attribute__((ext_vector_type(8)));
typedef __bf16 bf16x4 __attribute__((ext_vector_type(4)));
typedef float  f32x4  __attribute__((ext_vector_type(4)));

#define NPIX  3136      // 56*56 = 49*64 = 98*32 (no tails)
#define WIMG  56
#define CCH   128
#define NH    4
#define HD    32
// 32^-0.5 * log2(e): q pre-scaled so softmax uses exp2 directly
#define QSCALE 0.2550565470841439f

#if __has_builtin(__builtin_amdgcn_exp2f)
#define FEXP2(x) __builtin_amdgcn_exp2f(x)
#else
#define FEXP2(x) __expf((x) * 0.6931471805599453f)
#endif

// MFMA 16x16x32 fragment maps (HW-verified in R1/R2):
//   A[m=lane&15][k=(lane>>4)*8+j]   B[k=(lane>>4)*8+j][n=lane&15]
//   D: col(n)=lane&15, row(m)=(lane>>4)*4+reg
// Key permutation inside each 64-key block: storage s holds key 16*(s&3)+(s>>2)
// so QK chunk-c output (key 16c+col at lane col) packs to s=4*col+c (one b64),
// and vP is written pre-permuted to match (summation-index permutation = free).

// ---------------------------------------------------------------------------
// K1: qkv = qkv_w @ x + qkv_b as bf16 MFMA GEMM (M=384, K=128, N=6272).
// grid (49, 6, 2), block 256 = 4 waves; block = 64 outputs x 64 pixels.
// x-tile staged fp32->bf16 into LDS native [c][px]; B-frags via strided b16
// reads (~4-way banks = mild); A-frags = w rows, contiguous from global.
// Outputs: qT/kT [bh][px][d] (q pre-scaled), vT [b][px][c], vP [b][c][perm px].
// ---------------------------------------------------------------------------
__global__ __launch_bounds__(256) void k_qkv(
    const float* __restrict__ x, const float* __restrict__ qkv_w,
    const float* __restrict__ qkv_b,
    __bf16* __restrict__ qT, __bf16* __restrict__ kT,
    __bf16* __restrict__ vT, __bf16* __restrict__ vP)
{
    __shared__ __bf16 xl[CCH][68];                 // 64 px + pad (8B-aligned rows)
    const int tid = threadIdx.x;
    const int w = tid >> 6, lane = tid & 63;
    const int col = lane & 15, g = lane >> 4;
    const int px0 = blockIdx.x * 64;
    const int oslab = blockIdx.y;                  // 0-1 q, 2-3 k, 4-5 v
    const int b = blockIdx.z;
    const int obase = oslab * 64 + w * 16;

    {   // stage x[., px0..px0+63] -> bf16 LDS (coalesced float4 reads, b64 writes)
        const int pxg = tid & 15, cb = tid >> 4;
        const float* xp = x + (size_t)b * CCH * NPIX + px0 + 4 * pxg;
        #pragma unroll
        for (int pass = 0; pass < 8; ++pass) {
            const int c = cb + 16 * pass;
            const float4 xv = *(const float4*)(xp + (size_t)c * NPIX);
            bf16x4 v = {(__bf16)xv.x, (__bf16)xv.y, (__bf16)xv.z, (__bf16)xv.w};
            *(bf16x4*)&xl[c][4 * pxg] = v;
        }
    }
    __syncthreads();

    f32x4 acc[4];
    #pragma unroll
    for (int a = 0; a < 4; ++a) acc[a] = (f32x4){0.f, 0.f, 0.f, 0.f};

    const float* wrow = qkv_w + (size_t)(obase + col) * CCH;
    #pragma unroll
    for (int ks = 0; ks < 4; ++ks) {
        const int c0 = ks * 32 + g * 8;
        bf16x8 af;
        #pragma unroll
        for (int j = 0; j < 8; ++j) af[j] = (__bf16)wrow[c0 + j];   // 2x dwordx4 + cvt
        #pragma unroll
        for (int a = 0; a < 4; ++a) {
            bf16x8 bf_;
            #pragma unroll
            for (int j = 0; j < 8; ++j) bf_[j] = xl[c0 + j][16 * a + col];
            acc[a] = __builtin_amdgcn_mfma_f32_16x16x32_bf16(af, bf_, acc[a], 0, 0, 0);
        }
    }

    const int orow = obase + g * 4;                // first of this lane's 4 rows
    const f32x4 bias4 = *(const f32x4*)(qkv_b + orow);

    if (oslab < 2) {                               // ---- q (scaled) ----
        const int h = orow >> 5, d0 = orow & 31;
        __bf16* dst = qT + ((size_t)(b * NH + h) * NPIX) * HD + d0;
        #pragma unroll
        for (int a = 0; a < 4; ++a) {
            const int px = px0 + 16 * a + col;
            bf16x4 v;
            #pragma unroll
            for (int r = 0; r < 4; ++r) v[r] = (__bf16)((acc[a][r] + bias4[r]) * QSCALE);
            *(bf16x4*)(dst + (size_t)px * HD) = v;
        }
    } else if (oslab < 4) {                        // ---- k ----
        const int o2 = orow - 128;
        const int h = o2 >> 5, d0 = o2 & 31;
        __bf16* dst = kT + ((size_t)(b * NH + h) * NPIX) * HD + d0;
        #pragma unroll
        for (int a = 0; a < 4; ++a) {
            const int px = px0 + 16 * a + col;
            bf16x4 v;
            #pragma unroll
            for (int r = 0; r < 4; ++r) v[r] = (__bf16)(acc[a][r] + bias4[r]);
            *(bf16x4*)(dst + (size_t)px * HD) = v;
        }
    } else {                                       // ---- v: vT + permuted vP ----
        const int c = orow - 256;
        #pragma unroll
        for (int a = 0; a < 4; ++a) {
            const int px = px0 + 16 * a + col;
            bf16x4 v;
            #pragma unroll
            for (int r = 0; r < 4; ++r) v[r] = (__bf16)(acc[a][r] + bias4[r]);
            *(bf16x4*)(vT + ((size_t)(b * NPIX + px)) * CCH + c) = v;
            const int sp = px0 + 4 * col + a;      // permuted slot of key px
            #pragma unroll
            for (int r = 0; r < 4; ++r)
                vP[((size_t)(b * CCH + c + r)) * NPIX + sp] = v[r];
        }
    }
}

// ---------------------------------------------------------------------------
// K2: flash attention (split-K over 4 waves) + fused LePE in the epilogue.
// grid (98, 8), block 256. Ping-pong prefetch of next chunk's K/V overlaps
// VMEM with the exp->LDS->PV chain. Output layout [b][px][c] bf16 (attnT) so
// k_proj can take contiguous B-fragments.
// ---------------------------------------------------------------------------
__global__ __launch_bounds__(256) void k_attn(
    const __bf16* __restrict__ qT, const __bf16* __restrict__ kT,
    const __bf16* __restrict__ vP, const __bf16* __restrict__ vT,
    const float* __restrict__ lepe_w, const float* __restrict__ lepe_b,
    __bf16* __restrict__ attnT)
{
    __shared__ __bf16 P[4][32][72];        // per-wave P tile (2-way banks, 16B rows)
    __shared__ float  Opart[4][32][33];
    __shared__ float  lpart[4][32];
    __shared__ float  wl[32][25];          // this head's LePE weights
    __shared__ float  bl[32];

    const int tid = threadIdx.x;
    const int w = tid >> 6, lane = tid & 63;
    const int col = lane & 15, g = lane >> 4;
    const int bh = blockIdx.y, b = bh >> 2, h = bh & 3;
    const int qbase = blockIdx.x * 32;
    const size_t headoff = (size_t)bh * NPIX * HD;
    const int c0h = h * HD;

    for (int i = tid; i < 800; i += 256) ((float*)wl)[i] = lepe_w[c0h * 25 + i];
    if (tid < 32) bl[tid] = lepe_b[c0h + tid];

    const bf16x8 aqA = *(const bf16x8*)(qT + headoff + (size_t)(qbase + col) * HD + g * 8);
    const bf16x8 aqB = *(const bf16x8*)(qT + headoff + (size_t)(qbase + 16 + col) * HD + g * 8);

    f32x4 O[2][2];
    #pragma unroll
    for (int i = 0; i < 2; ++i)
        #pragma unroll
        for (int j = 0; j < 2; ++j) O[i][j] = (f32x4){0.f, 0.f, 0.f, 0.f};
    float lacc[2][4] = {{0.f,0.f,0.f,0.f},{0.f,0.f,0.f,0.f}};

    const __bf16* kTh   = kT + headoff;
    const __bf16* vrow0 = vP + (size_t)(b * CCH + c0h + col)      * NPIX;
    const __bf16* vrow1 = vP + (size_t)(b * CCH + c0h + 16 + col) * NPIX;

    const int cs = (49 * w) >> 2, ce = (49 * (w + 1)) >> 2;   // 12,12,12,13 chunks

#define LOADKV(DK, DV, KK) do { const int _k0 = (KK);                                     \
        _Pragma("unroll")                                                                 \
        for (int _c = 0; _c < 4; ++_c)                                                    \
            DK[_c] = *(const bf16x8*)(kTh + (size_t)(_k0 + 16 * _c + col) * HD + g * 8);  \
        DV[0] = *(const bf16x8*)(vrow0 + _k0      + g * 8);                               \
        DV[1] = *(const bf16x8*)(vrow0 + _k0 + 32 + g * 8);                               \
        DV[2] = *(const bf16x8*)(vrow1 + _k0      + g * 8);                               \
        DV[3] = *(const bf16x8*)(vrow1 + _k0 + 32 + g * 8); } while (0)

    auto compute = [&](const bf16x8* bk, const bf16x8* bv) {
        const f32x4 z = {0.f, 0.f, 0.f, 0.f};
        #pragma unroll
        for (int qh = 0; qh < 2; ++qh) {
            const bf16x8 aq = qh ? aqB : aqA;
            f32x4 s0 = __builtin_amdgcn_mfma_f32_16x16x32_bf16(aq, bk[0], z, 0, 0, 0);
            f32x4 s1 = __builtin_amdgcn_mfma_f32_16x16x32_bf16(aq, bk[1], z, 0, 0, 0);
            f32x4 s2 = __builtin_amdgcn_mfma_f32_16x16x32_bf16(aq, bk[2], z, 0, 0, 0);
            f32x4 s3 = __builtin_amdgcn_mfma_f32_16x16x32_bf16(aq, bk[3], z, 0, 0, 0);
            #pragma unroll
            for (int r = 0; r < 4; ++r) {
                const float p0 = FEXP2(s0[r]), p1 = FEXP2(s1[r]);
                const float p2 = FEXP2(s2[r]), p3 = FEXP2(s3[r]);
                lacc[qh][r] += (p0 + p1) + (p2 + p3);
                bf16x4 pv = {(__bf16)p0, (__bf16)p1, (__bf16)p2, (__bf16)p3};
                *(bf16x4*)&P[w][qh * 16 + g * 4 + r][4 * col] = pv;
            }
        }
        #pragma unroll
        for (int qh = 0; qh < 2; ++qh) {
            const bf16x8 ap0 = *(const bf16x8*)&P[w][qh * 16 + col][g * 8];
            const bf16x8 ap1 = *(const bf16x8*)&P[w][qh * 16 + col][32 + g * 8];
            O[qh][0] = __builtin_amdgcn_mfma_f32_16x16x32_bf16(ap0, bv[0], O[qh][0], 0, 0, 0);
            O[qh][0] = __builtin_amdgcn_mfma_f32_16x16x32_bf16(ap1, bv[1], O[qh][0], 0, 0, 0);
            O[qh][1] = __builtin_amdgcn_mfma_f32_16x16x32_bf16(ap0, bv[2], O[qh][1], 0, 0, 0);
            O[qh][1] = __builtin_amdgcn_mfma_f32_16x16x32_bf16(ap1, bv[3], O[qh][1], 0, 0, 0);
        }
    };

    bf16x8 kA[4], vA[4], kB[4], vBb[4];
    LOADKV(kA, vA, cs * 64);
    int cc = cs;
    while (cc + 2 <= ce) {                      // ping-pong software pipeline
        LOADKV(kB, vBb, (cc + 1) * 64);
        compute(kA, vA);
        const int kn = (cc + 2 < ce) ? (cc + 2) * 64 : cs * 64;  // dummy reload ok
        LOADKV(kA, vA, kn);
        compute(kB, vBb);
        cc += 2;
    }
    if (cc < ce) compute(kA, vA);               // odd tail (wave 3: 13 chunks)
#undef LOADKV

    #pragma unroll
    for (int qh = 0; qh < 2; ++qh)
        #pragma unroll
        for (int r = 0; r < 4; ++r) {
            float l = lacc[qh][r];
            l += __shfl_xor(l, 1);  l += __shfl_xor(l, 2);
            l += __shfl_xor(l, 4);  l += __shfl_xor(l, 8);
            if (col == 0) lpart[w][qh * 16 + g * 4 + r] = l;
        }
    #pragma unroll
    for (int qh = 0; qh < 2; ++qh)
        #pragma unroll
        for (int r = 0; r < 4; ++r) {
            Opart[w][qh * 16 + g * 4 + r][col]      = O[qh][0][r];
            Opart[w][qh * 16 + g * 4 + r][col + 16] = O[qh][1][r];
        }
    __syncthreads();

    // epilogue: reduce 4 wave-partials, normalize, add LePE+bias, store [px][c]
    const int q  = tid >> 3;                   // 0..31
    const int dq = (tid & 7) * 4;              // 0,4,...,28
    const int px = qbase + q;
    const float linv = 1.0f / (lpart[0][q] + lpart[1][q] + lpart[2][q] + lpart[3][q]);
    float o[4];
    #pragma unroll
    for (int i = 0; i < 4; ++i)
        o[i] = (Opart[0][q][dq + i] + Opart[1][q][dq + i] +
                Opart[2][q][dq + i] + Opart[3][q][dq + i]) * linv + bl[dq + i];

    const int py = px / WIMG, pxx = px % WIMG;
    const __bf16* vtb = vT + ((size_t)b * NPIX) * CCH + c0h + dq;
    #pragma unroll
    for (int dy = 0; dy < 5; ++dy) {
        const int yy = py + dy - 2;
        if (yy < 0 || yy >= WIMG) continue;
        #pragma unroll
        for (int dx = 0; dx < 5; ++dx) {
            const int xx = pxx + dx - 2;
            if (xx < 0 || xx >= WIMG) continue;
            const bf16x4 vv = *(const bf16x4*)(vtb + (size_t)(yy * WIMG + xx) * CCH);
            const int tap = dy * 5 + dx;
            #pragma unroll
            for (int i = 0; i < 4; ++i) o[i] += (float)vv[i] * wl[dq + i][tap];
        }
    }
    bf16x4 ov = {(__bf16)o[0], (__bf16)o[1], (__bf16)o[2], (__bf16)o[3]};
    *(bf16x4*)(attnT + ((size_t)(b * NPIX + px)) * CCH + c0h + dq) = ov;
}

// ---------------------------------------------------------------------------
// K3: out = proj_w @ (attn+lepe) + proj_b, bf16 MFMA, zero LDS.
// grid (98, 2, 2), block 256 = 4 waves; block = 64 outputs x 32 pixels.
// A-frags = proj_w rows (fp32->bf16), B-frags = attnT contiguous 16B loads.
// ---------------------------------------------------------------------------
__global__ __launch_bounds__(256) void k_proj(
    const __bf16* __restrict__ attnT, const float* __restrict__ proj_w,
    const float* __restrict__ proj_b, float* __restrict__ out)
{
    const int tid = threadIdx.x;
    const int w = tid >> 6, lane = tid & 63;
    const int col = lane & 15, g = lane >> 4;
    const int px0 = blockIdx.x * 32;
    const int obase = blockIdx.y * 64 + w * 16;
    const int b = blockIdx.z;

    const float* wrow = proj_w + (size_t)(obase + col) * CCH;
    const __bf16* abase = attnT + (size_t)(b * NPIX + px0) * CCH;

    f32x4 acc[2];
    acc[0] = (f32x4){0.f, 0.f, 0.f, 0.f};
    acc[1] = (f32x4){0.f, 0.f, 0.f, 0.f};

    #pragma unroll
    for (int ks = 0; ks < 4; ++ks) {
        const int c0 = ks * 32 + g * 8;
        bf16x8 af;
        #pragma unroll
        for (int j = 0; j < 8; ++j) af[j] = (__bf16)wrow[c0 + j];
        #pragma unroll
        for (int a = 0; a < 2; ++a) {
            const bf16x8 bf_ = *(const bf16x8*)(abase + (size_t)(16 * a + col) * CCH + c0);
            acc[a] = __builtin_amdgcn_mfma_f32_16x16x32_bf16(af, bf_, acc[a], 0, 0, 0);
        }
    }

    const f32x4 pb = *(const f32x4*)(proj_b + obase + g * 4);
    #pragma unroll
    for (int a = 0; a < 2; ++a)
        #pragma unroll
        for (int r = 0; r < 4; ++r)
            out[(size_t)(b * CCH + obase + g * 4 + r) * NPIX + px0 + 16 * a + col] =
                acc[a][r] + pb[r];
}

// ---------------------------------------------------------------------------
extern "C" void kernel_launch(void* const* d_in, const int* in_sizes, int n_in,
                              void* d_out, int out_size, void* d_ws, size_t ws_size,
                              hipStream_t stream)
{
    const float* x      = (const float*)d_in[0];
    const float* qkv_w  = (const float*)d_in[1];
    const float* qkv_b  = (const float*)d_in[2];
    const float* lepe_w = (const float*)d_in[3];
    const float* lepe_b = (const float*)d_in[4];
    const float* proj_w = (const float*)d_in[5];
    const float* proj_b = (const float*)d_in[6];
    float* out = (float*)d_out;

    char* p = (char*)d_ws;                                   // 8.03 MB total
    __bf16* qT = (__bf16*)p;    p += (size_t)2 * NH * NPIX * HD * 2;
    __bf16* kT = (__bf16*)p;    p += (size_t)2 * NH * NPIX * HD * 2;
    __bf16* vT = (__bf16*)p;    p += (size_t)2 * NPIX * CCH * 2;
    __bf16* vP = (__bf16*)p;    p += (size_t)2 * CCH * NPIX * 2;
    __bf16* attnT = (__bf16*)p;

    k_qkv <<<dim3(49, 6, 2), dim3(256), 0, stream>>>(x, qkv_w, qkv_b, qT, kT, vT, vP);
    k_attn<<<dim3(98, 8),    dim3(256), 0, stream>>>(qT, kT, vP, vT, lepe_w, lepe_b, attnT);
    k_proj<<<dim3(98, 2, 2), dim3(256), 0, stream>>>(attnT, proj_w, proj_b, out);
}